// Round 3
// baseline (1349.749 us; speedup 1.0000x reference)
//
#include <hip/hip_runtime.h>
#include <hip/hip_bf16.h>
#include <math.h>

typedef unsigned char  u8;
typedef unsigned int   u32;
typedef __attribute__((ext_vector_type(8)))  int   int8v;
typedef __attribute__((ext_vector_type(16))) float f32x16;

typedef __attribute__((address_space(3))) void lds_void;
typedef __attribute__((address_space(1))) void gbl_void;

#define IGNORE_INDEX (-100)

// ---------------- fp32 -> OCP e4m3 with explicit RNE ----------------
__device__ __forceinline__ u8 f32_to_e4m3(float f) {
    union { float f; u32 u; } v; v.f = f;
    u32 s  = (v.u >> 24) & 0x80u;
    u32 au = v.u & 0x7FFFFFFFu;
    float a = __uint_as_float(au);
    if (a >= 448.0f) return (u8)(s | 0x7E);          // clamp to max normal
    int e = (int)(au >> 23) - 127;
    if (e >= -6) {
        u32 m    = au & 0x7FFFFFu;
        u32 keep = m >> 20;
        u32 rest = m & 0xFFFFFu;
        keep += (rest > 0x80000u) || (rest == 0x80000u && (keep & 1u));
        u32 code = ((u32)(e + 7) << 3) + keep;        // mantissa carry bumps exponent
        if (code > 0x7E) code = 0x7E;
        return (u8)(s | code);
    } else {
        int q = (int)rintf(a * 512.0f);               // subnormal quantum 2^-9 (RNE)
        return (u8)(s | (u32)q);                      // q==8 lands on min-normal encoding
    }
}

// ---------------- fp32 -> fp8 conversion (memory-bound), pre-scaled ----------------
__global__ __launch_bounds__(256) void cvt_f32_fp8(const float* __restrict__ in,
                                                   u8* __restrict__ out,
                                                   float scale, long n) {
    long i = (long)blockIdx.x * blockDim.x + threadIdx.x;
    long stride = (long)gridDim.x * blockDim.x;
    for (long j = i * 16; j + 15 < n; j += stride * 16) {
        u8 tmp[16];
#pragma unroll
        for (int t = 0; t < 4; ++t) {
            float4 f = *(const float4*)(in + j + t * 4);
            tmp[t * 4 + 0] = f32_to_e4m3(f.x * scale);
            tmp[t * 4 + 1] = f32_to_e4m3(f.y * scale);
            tmp[t * 4 + 2] = f32_to_e4m3(f.z * scale);
            tmp[t * 4 + 3] = f32_to_e4m3(f.w * scale);
        }
        *(int4*)(out + j) = *(const int4*)tmp;
    }
}

// ---------------- fused MX-fp8 GEMM tile + online LSE partials ----------------
// BM=128, BN=128, BK=128 bytes. 256 threads = 4 waves (2x2), each wave 64x64
// via 2x2 mfma_scale_f32_32x32x64_f8f6f4.
//
// LDS is staged in MFMA-FRAGMENT ORDER: region s = (i2<<2)|(ks<<1)|h (1024 B)
// holds at lane*16 exactly the bytes lane needs for fragment half h of
// (row-band i2, k-step ks): row = i2*32 + (lane&31),
// k = ks*64 + (lane>>5)*32 + h*16. global_load_lds is a source-side gather
// (dest = base + lane*16, m104), so staging this order is free; fragment
// reads become ds_read_b128 at uniform_base + lane*16 -> zero bank conflicts
// and near-zero address VALU (one v-addr + immediate offsets).
__global__ __launch_bounds__(256) void gemm_lse_partial(
    const u8* __restrict__ A8,      // [N][H] fp8 (x*8)
    const u8* __restrict__ B8,      // [V][H] fp8 (W*16)
    float2* __restrict__ partials,  // [N][VT]  (m, sumexp)
    int H, int V, int VT)
{
    __shared__ __align__(16) u8 As[16 * 1024];   // 16 KB
    __shared__ __align__(16) u8 Bs[16 * 1024];   // 16 KB

    const int tid  = threadIdx.x;
    const int w    = tid >> 6;
    const int lane = tid & 63;
    const int wm   = w >> 1, wn = w & 1;
    const int ln32 = lane & 31;
    const int khalf = lane >> 5;

    const int mBase = blockIdx.x * 128;
    const int vTile = blockIdx.y;
    const int vBase = vTile * 128;

    // ---- staging source pointers: wave w stages row-band w (rows 32w..32w+31)
    // for all 4 (ks,h) combos; lane -> row w*32+ln32, k-offset cOff + khalf*32.
    const size_t Hs = (size_t)H;
    const size_t aRow = (size_t)(mBase + w * 32 + ln32);
    int vr = vBase + w * 32 + ln32; if (vr >= V) vr = V - 1;
    const u8* aBase = A8 + aRow * Hs + khalf * 32;
    const u8* bBase = B8 + (size_t)vr * Hs + khalf * 32;
    // c = (ks<<1)|h -> koff = ks*64 + h*16
    const int cOff0 = 0, cOff1 = 16, cOff2 = 64, cOff3 = 80;

    f32x16 acc[2][2];
#pragma unroll
    for (int i = 0; i < 2; ++i)
#pragma unroll
        for (int j = 0; j < 2; ++j)
#pragma unroll
            for (int r = 0; r < 16; ++r) acc[i][j][r] = 0.0f;

    const int scaleA = 0x7C7C7C7C;  // E8M0 124 = 2^-3 (undo x*8)
    const int scaleB = 0x7B7B7B7B;  // E8M0 123 = 2^-4 (undo W*16)

    // per-lane LDS read bases (uniform + lane*16)
    const u8* aRd = As + lane * 16;
    const u8* bRd = Bs + lane * 16;

    for (int k0 = 0; k0 < H; k0 += 128) {
        u8* aDst = (u8*)As + w * 4096;
        u8* bDst = (u8*)Bs + w * 4096;
        __builtin_amdgcn_global_load_lds((gbl_void*)(aBase + k0 + cOff0), (lds_void*)(aDst       ), 16, 0, 0);
        __builtin_amdgcn_global_load_lds((gbl_void*)(aBase + k0 + cOff1), (lds_void*)(aDst + 1024), 16, 0, 0);
        __builtin_amdgcn_global_load_lds((gbl_void*)(aBase + k0 + cOff2), (lds_void*)(aDst + 2048), 16, 0, 0);
        __builtin_amdgcn_global_load_lds((gbl_void*)(aBase + k0 + cOff3), (lds_void*)(aDst + 3072), 16, 0, 0);
        __builtin_amdgcn_global_load_lds((gbl_void*)(bBase + k0 + cOff0), (lds_void*)(bDst       ), 16, 0, 0);
        __builtin_amdgcn_global_load_lds((gbl_void*)(bBase + k0 + cOff1), (lds_void*)(bDst + 1024), 16, 0, 0);
        __builtin_amdgcn_global_load_lds((gbl_void*)(bBase + k0 + cOff2), (lds_void*)(bDst + 2048), 16, 0, 0);
        __builtin_amdgcn_global_load_lds((gbl_void*)(bBase + k0 + cOff3), (lds_void*)(bDst + 3072), 16, 0, 0);
        __syncthreads();

#pragma unroll
        for (int ks = 0; ks < 2; ++ks) {
            int8v af[2], bf[2];
#pragma unroll
            for (int i = 0; i < 2; ++i) {
                // region s = ((wm*2+i)<<2)|(ks<<1)|h; offset = s*1024
                int sA = ((wm * 2 + i) * 4 + ks * 2) * 1024;
                int4 lo = *(const int4*)(aRd + sA);
                int4 hi = *(const int4*)(aRd + sA + 1024);
                int8v a; a[0]=lo.x; a[1]=lo.y; a[2]=lo.z; a[3]=lo.w;
                         a[4]=hi.x; a[5]=hi.y; a[6]=hi.z; a[7]=hi.w;
                af[i] = a;
                int sB = ((wn * 2 + i) * 4 + ks * 2) * 1024;
                lo = *(const int4*)(bRd + sB);
                hi = *(const int4*)(bRd + sB + 1024);
                int8v b; b[0]=lo.x; b[1]=lo.y; b[2]=lo.z; b[3]=lo.w;
                         b[4]=hi.x; b[5]=hi.y; b[6]=hi.z; b[7]=hi.w;
                bf[i] = b;
            }
#pragma unroll
            for (int i = 0; i < 2; ++i)
#pragma unroll
                for (int j = 0; j < 2; ++j)
                    acc[i][j] = __builtin_amdgcn_mfma_scale_f32_32x32x64_f8f6f4(
                        af[i], bf[j], acc[i][j], 0, 0, 0, scaleA, 0, scaleB);
        }
        __syncthreads();
    }

    // ---- online-softmax partial per row of the 128x128 tile ----
    // C/D 32x32 layout (m74/m101, fmt-independent): col=lane&31,
    // row=(reg&3)+8*(reg>>2)+4*(lane>>5).
    bool vj[2];
#pragma unroll
    for (int j = 0; j < 2; ++j)
        vj[j] = (vBase + wn * 64 + j * 32 + ln32) < V;

    float2* red = (float2*)As;   // reuse LDS: [128 rows][2 wave-halves]

#pragma unroll
    for (int i = 0; i < 2; ++i) {
#pragma unroll
        for (int r = 0; r < 16; ++r) {
            float v0 = vj[0] ? acc[i][0][r] : -INFINITY;
            float v1 = vj[1] ? acc[i][1][r] : -INFINITY;
            float m = fmaxf(v0, v1);
#pragma unroll
            for (int o = 1; o < 32; o <<= 1)
                m = fmaxf(m, __shfl_xor(m, o, 64));
            float s = 0.0f;
            if (vj[0]) s += __expf(acc[i][0][r] - m);
            if (vj[1]) s += __expf(acc[i][1][r] - m);
#pragma unroll
            for (int o = 1; o < 32; o <<= 1)
                s += __shfl_xor(s, o, 64);
            if (ln32 == 0) {
                int row = wm * 64 + i * 32 + (r & 3) + 8 * (r >> 2) + 4 * khalf;
                red[row * 2 + wn] = make_float2(m, s);
            }
        }
    }
    __syncthreads();

    if (tid < 128) {
        float2 p0 = red[tid * 2 + 0];
        float2 p1 = red[tid * 2 + 1];
        float m = fmaxf(p0.x, p1.x);
        float s = p0.y * __expf(p0.x - m) + p1.y * __expf(p1.x - m);
        partials[(size_t)(mBase + tid) * VT + vTile] = make_float2(m, s);
    }
}

// ---------------- per-row: merge partials -> LSE, fp32 label dot ----------------
__global__ __launch_bounds__(256) void row_final(
    const float* __restrict__ x,      // [N][H] fp32
    const float* __restrict__ W,      // [V][H] fp32
    const int* __restrict__ y,        // [N]
    const float2* __restrict__ partials, // [N][VT]
    float* __restrict__ nll, float* __restrict__ valid,
    int H, int V, int VT)
{
    const int n = blockIdx.x;
    const int t = threadIdx.x;
    const int yn = y[n];
    const bool ok = (yn != IGNORE_INDEX);

    // label logit in full fp32
    float dsum = 0.0f;
    if (ok) {
        int cy = yn; if (cy < 0) cy = 0; if (cy >= V) cy = V - 1;
        const float4* xr = (const float4*)(x + (size_t)n * H);
        const float4* wr = (const float4*)(W + (size_t)cy * H);
        int nf4 = H >> 2;
        for (int i = t; i < nf4; i += 256) {
            float4 a = xr[i], b = wr[i];
            dsum += a.x * b.x + a.y * b.y + a.z * b.z + a.w * b.w;
        }
    }

    // merge this row's LSE partials
    float m = -INFINITY, s = 0.0f;
    const float2* pr = partials + (size_t)n * VT;
    for (int i = t; i < VT; i += 256) {
        float2 p = pr[i];
        float nm = fmaxf(m, p.x);
        s = s * __expf(m - nm) + p.y * __expf(p.x - nm);
        m = nm;
    }

    __shared__ float rm[256], rs[256], rd[256];
    rm[t] = m; rs[t] = s; rd[t] = dsum;
    __syncthreads();
    for (int o = 128; o > 0; o >>= 1) {
        if (t < o) {
            float m2 = rm[t + o], s2 = rs[t + o];
            float nm = fmaxf(rm[t], m2);
            rs[t] = rs[t] * __expf(rm[t] - nm) + s2 * __expf(m2 - nm);
            rm[t] = nm;
            rd[t] += rd[t + o];
        }
        __syncthreads();
    }
    if (t == 0) {
        float lse = rm[0] + __logf(rs[0]);
        nll[n]   = ok ? (lse - rd[0]) : 0.0f;
        valid[n] = ok ? 1.0f : 0.0f;
    }
}

// ---------------- final: loss = sum(nll) / max(sum(valid), 1) ----------------
__global__ __launch_bounds__(1024) void final_loss(
    const float* __restrict__ nll, const float* __restrict__ valid,
    float* __restrict__ out, int n)
{
    __shared__ float ss[1024], sv[1024];
    const int t = threadIdx.x;
    float a = 0.0f, b = 0.0f;
    for (int i = t; i < n; i += 1024) { a += nll[i]; b += valid[i]; }
    ss[t] = a; sv[t] = b;
    __syncthreads();
    for (int o = 512; o > 0; o >>= 1) {
        if (t < o) { ss[t] += ss[t + o]; sv[t] += sv[t + o]; }
        __syncthreads();
    }
    if (t == 0) out[0] = ss[0] / fmaxf(sv[0], 1.0f);
}

extern "C" void kernel_launch(void* const* d_in, const int* in_sizes, int n_in,
                              void* d_out, int out_size, void* d_ws, size_t ws_size,
                              hipStream_t stream) {
    const float* x = (const float*)d_in[0];
    const float* W = (const float*)d_in[1];
    const int*   y = (const int*)d_in[2];

    const long xsz = in_sizes[0];            // N*H
    const long wsz = in_sizes[1];            // V*H
    const int  N   = in_sizes[2];
    const int  H   = (int)(xsz / N);         // 2048
    const int  V   = (int)(wsz / H);         // 50257
    const int  VT  = (V + 127) / 128;        // 393
    const int  MT  = N / 128;                // 32

    char* ws = (char*)d_ws;
    size_t off = 0;
    u8* Wf8 = (u8*)(ws + off); off += (size_t)wsz; off = (off + 255) & ~(size_t)255;
    u8* Xf8 = (u8*)(ws + off); off += (size_t)xsz; off = (off + 255) & ~(size_t)255;
    float2* partials = (float2*)(ws + off); off += (size_t)N * VT * sizeof(float2); off = (off + 255) & ~(size_t)255;
    float* nll   = (float*)(ws + off); off += (size_t)N * 4;
    float* valid = (float*)(ws + off); off += (size_t)N * 4;

    int wBlocks = (int)((wsz / 16 + 255) / 256);
    int xBlocks = (int)((xsz / 16 + 255) / 256);
    cvt_f32_fp8<<<wBlocks, 256, 0, stream>>>(W, Wf8, 16.0f, wsz);
    cvt_f32_fp8<<<xBlocks, 256, 0, stream>>>(x, Xf8, 8.0f, xsz);

    dim3 grid(MT, VT);   // mTile fast -> consecutive blocks share the W tile (L2 reuse)
    gemm_lse_partial<<<grid, 256, 0, stream>>>(Xf8, Wf8, partials, H, V, VT);

    row_final<<<N, 256, 0, stream>>>(x, W, y, partials, nll, valid, H, V, VT);
    final_loss<<<1, 1024, 0, stream>>>(nll, valid, (float*)d_out, N);
}

// Round 4
// 1229.059 us; speedup vs baseline: 1.0982x; 1.0982x over previous
//
#include <hip/hip_runtime.h>
#include <hip/hip_bf16.h>
#include <math.h>

typedef unsigned char  u8;
typedef unsigned int   u32;
typedef __attribute__((ext_vector_type(8)))  int   int8v;
typedef __attribute__((ext_vector_type(16))) float f32x16;

typedef __attribute__((address_space(3))) void lds_void;
typedef __attribute__((address_space(1))) void gbl_void;

#define IGNORE_INDEX (-100)

// ---------------- fp32 -> OCP e4m3 with explicit RNE ----------------
__device__ __forceinline__ u8 f32_to_e4m3(float f) {
    union { float f; u32 u; } v; v.f = f;
    u32 s  = (v.u >> 24) & 0x80u;
    u32 au = v.u & 0x7FFFFFFFu;
    float a = __uint_as_float(au);
    if (a >= 448.0f) return (u8)(s | 0x7E);          // clamp to max normal
    int e = (int)(au >> 23) - 127;
    if (e >= -6) {
        u32 m    = au & 0x7FFFFFu;
        u32 keep = m >> 20;
        u32 rest = m & 0xFFFFFu;
        keep += (rest > 0x80000u) || (rest == 0x80000u && (keep & 1u));
        u32 code = ((u32)(e + 7) << 3) + keep;        // mantissa carry bumps exponent
        if (code > 0x7E) code = 0x7E;
        return (u8)(s | code);
    } else {
        int q = (int)rintf(a * 512.0f);               // subnormal quantum 2^-9 (RNE)
        return (u8)(s | (u32)q);                      // q==8 lands on min-normal encoding
    }
}

// ---------------- fp32 -> fp8, packed into MFMA-fragment order ----------------
// Packed layout (matches gemm LDS exactly):
//   P[panel][kc][s][lane][b],  s = i2*4 + ks*2 + h  (i2=row band, ks=k-step, h=16B half)
//   lane = khalf*32 + ln32  ->  row = panel*128 + i2*32 + ln32
//                               col = kc*128 + ks*64 + khalf*32 + h*16 + b
// Block = one (panel, kc) unit: 128 rows x 128 cols. Read row-major coalesced,
// scatter through LDS, dump 16KB contiguous.
__global__ __launch_bounds__(256) void cvt_pack_fp8(const float* __restrict__ in,
                                                    u8* __restrict__ out,
                                                    float scale, int H, int nRows) {
    __shared__ __align__(16) u8 lds[16384];
    const int kc    = blockIdx.x;
    const int panel = blockIdx.y;
    const int t     = threadIdx.x;

#pragma unroll
    for (int it = 0; it < 4; ++it) {
        int u  = it * 256 + t;          // 0..1023
        int r  = u >> 3;                // 0..127
        int cc = u & 7;                 // 16-col chunk within kc
        int row = panel * 128 + r;
        u8 tmp[16];
        if (row < nRows) {
            const float* src = in + (size_t)row * H + kc * 128 + cc * 16;
#pragma unroll
            for (int p = 0; p < 4; ++p) {
                float4 f = *(const float4*)(src + p * 4);
                tmp[p * 4 + 0] = f32_to_e4m3(f.x * scale);
                tmp[p * 4 + 1] = f32_to_e4m3(f.y * scale);
                tmp[p * 4 + 2] = f32_to_e4m3(f.z * scale);
                tmp[p * 4 + 3] = f32_to_e4m3(f.w * scale);
            }
        } else {
#pragma unroll
            for (int p = 0; p < 16; ++p) tmp[p] = 0;   // padded vocab rows -> 0.0
        }
        int i2 = r >> 5, ln32 = r & 31;
        int ks = cc >> 2, khalf = (cc >> 1) & 1, h = cc & 1;
        int s  = i2 * 4 + ks * 2 + h;
        int lane = khalf * 32 + ln32;
        *(int4*)(lds + s * 1024 + lane * 16) = *(const int4*)tmp;
    }
    __syncthreads();

    u8* dst = out + ((size_t)panel * gridDim.x + kc) * 16384;
    const int4* l4 = (const int4*)lds;
    int4* d4 = (int4*)dst;
#pragma unroll
    for (int p = 0; p < 4; ++p)
        d4[p * 256 + t] = l4[p * 256 + t];
}

// ---------------- fused MX-fp8 GEMM tile + online LSE partials ----------------
// BM=128, BN=128, BK=128 bytes. 256 threads = 4 waves (2x2), each wave 64x64
// via 2x2 mfma_scale_f32_32x32x64_f8f6f4. Operands arrive PRE-PACKED in
// fragment order, so every global_load_lds reads 1024 contiguous bytes
// (perfect coalescing) and fragment ds_read_b128s are uniform_base + lane*16
// (zero bank conflicts, near-zero address VALU).
__global__ __launch_bounds__(256) void gemm_lse_partial(
    const u8* __restrict__ Ap,      // packed [MT][KC][16][64][16] fp8 (x*8)
    const u8* __restrict__ Bp,      // packed [VT][KC][16][64][16] fp8 (W*16)
    float2* __restrict__ partials,  // [N][VT]  (m, sumexp)
    int KC, int V, int VT)
{
    __shared__ __align__(16) u8 As[16 * 1024];   // 16 KB
    __shared__ __align__(16) u8 Bs[16 * 1024];   // 16 KB

    const int tid  = threadIdx.x;
    const int w    = tid >> 6;
    const int lane = tid & 63;
    const int wm   = w >> 1, wn = w & 1;
    const int ln32 = lane & 31;
    const int khalf = lane >> 5;

    const int mBase = blockIdx.x * 128;
    const int vTile = blockIdx.y;
    const int vBase = vTile * 128;

    f32x16 acc[2][2];
#pragma unroll
    for (int i = 0; i < 2; ++i)
#pragma unroll
        for (int j = 0; j < 2; ++j)
#pragma unroll
            for (int r = 0; r < 16; ++r) acc[i][j][r] = 0.0f;

    const int scaleA = 0x7C7C7C7C;  // E8M0 124 = 2^-3 (undo x*8)
    const int scaleB = 0x7B7B7B7B;  // E8M0 123 = 2^-4 (undo W*16)

    // staging source: wave w stages regions w*4..w*4+3 (4KB contiguous)
    const u8* aSrc = Ap + ((size_t)blockIdx.x * KC) * 16384 + (w * 4096 + lane * 16);
    const u8* bSrc = Bp + ((size_t)vTile      * KC) * 16384 + (w * 4096 + lane * 16);
    u8* aDst = (u8*)As + w * 4096;
    u8* bDst = (u8*)Bs + w * 4096;

    const u8* aRd = As + lane * 16;
    const u8* bRd = Bs + lane * 16;

    for (int kc = 0; kc < KC; ++kc) {
        __builtin_amdgcn_global_load_lds((gbl_void*)(aSrc       ), (lds_void*)(aDst       ), 16, 0, 0);
        __builtin_amdgcn_global_load_lds((gbl_void*)(aSrc + 1024), (lds_void*)(aDst + 1024), 16, 0, 0);
        __builtin_amdgcn_global_load_lds((gbl_void*)(aSrc + 2048), (lds_void*)(aDst + 2048), 16, 0, 0);
        __builtin_amdgcn_global_load_lds((gbl_void*)(aSrc + 3072), (lds_void*)(aDst + 3072), 16, 0, 0);
        __builtin_amdgcn_global_load_lds((gbl_void*)(bSrc       ), (lds_void*)(bDst       ), 16, 0, 0);
        __builtin_amdgcn_global_load_lds((gbl_void*)(bSrc + 1024), (lds_void*)(bDst + 1024), 16, 0, 0);
        __builtin_amdgcn_global_load_lds((gbl_void*)(bSrc + 2048), (lds_void*)(bDst + 2048), 16, 0, 0);
        __builtin_amdgcn_global_load_lds((gbl_void*)(bSrc + 3072), (lds_void*)(bDst + 3072), 16, 0, 0);
        aSrc += 16384; bSrc += 16384;
        __syncthreads();

#pragma unroll
        for (int ks = 0; ks < 2; ++ks) {
            int8v af[2], bf[2];
#pragma unroll
            for (int i = 0; i < 2; ++i) {
                int sA = ((wm * 2 + i) * 4 + ks * 2) * 1024;
                int4 lo = *(const int4*)(aRd + sA);
                int4 hi = *(const int4*)(aRd + sA + 1024);
                int8v a; a[0]=lo.x; a[1]=lo.y; a[2]=lo.z; a[3]=lo.w;
                         a[4]=hi.x; a[5]=hi.y; a[6]=hi.z; a[7]=hi.w;
                af[i] = a;
                int sB = ((wn * 2 + i) * 4 + ks * 2) * 1024;
                lo = *(const int4*)(bRd + sB);
                hi = *(const int4*)(bRd + sB + 1024);
                int8v b; b[0]=lo.x; b[1]=lo.y; b[2]=lo.z; b[3]=lo.w;
                         b[4]=hi.x; b[5]=hi.y; b[6]=hi.z; b[7]=hi.w;
                bf[i] = b;
            }
#pragma unroll
            for (int i = 0; i < 2; ++i)
#pragma unroll
                for (int j = 0; j < 2; ++j)
                    acc[i][j] = __builtin_amdgcn_mfma_scale_f32_32x32x64_f8f6f4(
                        af[i], bf[j], acc[i][j], 0, 0, 0, scaleA, 0, scaleB);
        }
        __syncthreads();
    }

    // ---- online-softmax partial per row of the 128x128 tile ----
    // C/D 32x32 layout (m74/m101, fmt-independent): col=lane&31,
    // row=(reg&3)+8*(reg>>2)+4*(lane>>5).
    bool vj[2];
#pragma unroll
    for (int j = 0; j < 2; ++j)
        vj[j] = (vBase + wn * 64 + j * 32 + ln32) < V;

    float2* red = (float2*)As;   // reuse LDS: [128 rows][2 wave-halves]

#pragma unroll
    for (int i = 0; i < 2; ++i) {
#pragma unroll
        for (int r = 0; r < 16; ++r) {
            float v0 = vj[0] ? acc[i][0][r] : -INFINITY;
            float v1 = vj[1] ? acc[i][1][r] : -INFINITY;
            float m = fmaxf(v0, v1);
#pragma unroll
            for (int o = 1; o < 32; o <<= 1)
                m = fmaxf(m, __shfl_xor(m, o, 64));
            float s = 0.0f;
            if (vj[0]) s += __expf(acc[i][0][r] - m);
            if (vj[1]) s += __expf(acc[i][1][r] - m);
#pragma unroll
            for (int o = 1; o < 32; o <<= 1)
                s += __shfl_xor(s, o, 64);
            if (ln32 == 0) {
                int row = wm * 64 + i * 32 + (r & 3) + 8 * (r >> 2) + 4 * khalf;
                red[row * 2 + wn] = make_float2(m, s);
            }
        }
    }
    __syncthreads();

    if (tid < 128) {
        float2 p0 = red[tid * 2 + 0];
        float2 p1 = red[tid * 2 + 1];
        float m = fmaxf(p0.x, p1.x);
        float s = p0.y * __expf(p0.x - m) + p1.y * __expf(p1.x - m);
        partials[(size_t)(mBase + tid) * VT + vTile] = make_float2(m, s);
    }
}

// ---------------- per-row: merge partials -> LSE, fp32 label dot ----------------
__global__ __launch_bounds__(256) void row_final(
    const float* __restrict__ x,      // [N][H] fp32
    const float* __restrict__ W,      // [V][H] fp32
    const int* __restrict__ y,        // [N]
    const float2* __restrict__ partials, // [N][VT]
    float* __restrict__ nll, float* __restrict__ valid,
    int H, int V, int VT)
{
    const int n = blockIdx.x;
    const int t = threadIdx.x;
    const int yn = y[n];
    const bool ok = (yn != IGNORE_INDEX);

    // label logit in full fp32
    float dsum = 0.0f;
    if (ok) {
        int cy = yn; if (cy < 0) cy = 0; if (cy >= V) cy = V - 1;
        const float4* xr = (const float4*)(x + (size_t)n * H);
        const float4* wr = (const float4*)(W + (size_t)cy * H);
        int nf4 = H >> 2;
        for (int i = t; i < nf4; i += 256) {
            float4 a = xr[i], b = wr[i];
            dsum += a.x * b.x + a.y * b.y + a.z * b.z + a.w * b.w;
        }
    }

    // merge this row's LSE partials
    float m = -INFINITY, s = 0.0f;
    const float2* pr = partials + (size_t)n * VT;
    for (int i = t; i < VT; i += 256) {
        float2 p = pr[i];
        float nm = fmaxf(m, p.x);
        s = s * __expf(m - nm) + p.y * __expf(p.x - nm);
        m = nm;
    }

    __shared__ float rm[256], rs[256], rd[256];
    rm[t] = m; rs[t] = s; rd[t] = dsum;
    __syncthreads();
    for (int o = 128; o > 0; o >>= 1) {
        if (t < o) {
            float m2 = rm[t + o], s2 = rs[t + o];
            float nm = fmaxf(rm[t], m2);
            rs[t] = rs[t] * __expf(rm[t] - nm) + s2 * __expf(m2 - nm);
            rm[t] = nm;
            rd[t] += rd[t + o];
        }
        __syncthreads();
    }
    if (t == 0) {
        float lse = rm[0] + __logf(rs[0]);
        nll[n]   = ok ? (lse - rd[0]) : 0.0f;
        valid[n] = ok ? 1.0f : 0.0f;
    }
}

// ---------------- final: loss = sum(nll) / max(sum(valid), 1) ----------------
__global__ __launch_bounds__(1024) void final_loss(
    const float* __restrict__ nll, const float* __restrict__ valid,
    float* __restrict__ out, int n)
{
    __shared__ float ss[1024], sv[1024];
    const int t = threadIdx.x;
    float a = 0.0f, b = 0.0f;
    for (int i = t; i < n; i += 1024) { a += nll[i]; b += valid[i]; }
    ss[t] = a; sv[t] = b;
    __syncthreads();
    for (int o = 512; o > 0; o >>= 1) {
        if (t < o) { ss[t] += ss[t + o]; sv[t] += sv[t + o]; }
        __syncthreads();
    }
    if (t == 0) out[0] = ss[0] / fmaxf(sv[0], 1.0f);
}

extern "C" void kernel_launch(void* const* d_in, const int* in_sizes, int n_in,
                              void* d_out, int out_size, void* d_ws, size_t ws_size,
                              hipStream_t stream) {
    const float* x = (const float*)d_in[0];
    const float* W = (const float*)d_in[1];
    const int*   y = (const int*)d_in[2];

    const long xsz = in_sizes[0];            // N*H
    const long wsz = in_sizes[1];            // V*H
    const int  N   = in_sizes[2];
    const int  H   = (int)(xsz / N);         // 2048
    const int  V   = (int)(wsz / H);         // 50257
    const int  VT  = (V + 127) / 128;        // 393
    const int  MT  = N / 128;                // 32
    const int  KC  = H / 128;                // 16

    char* ws = (char*)d_ws;
    size_t off = 0;
    u8* Wp = (u8*)(ws + off); off += (size_t)VT * KC * 16384; off = (off + 255) & ~(size_t)255;
    u8* Xp = (u8*)(ws + off); off += (size_t)MT * KC * 16384; off = (off + 255) & ~(size_t)255;
    float2* partials = (float2*)(ws + off); off += (size_t)N * VT * sizeof(float2); off = (off + 255) & ~(size_t)255;
    float* nll   = (float*)(ws + off); off += (size_t)N * 4;
    float* valid = (float*)(ws + off); off += (size_t)N * 4;

    cvt_pack_fp8<<<dim3(KC, VT), 256, 0, stream>>>(W, Wp, 16.0f, H, V);
    cvt_pack_fp8<<<dim3(KC, MT), 256, 0, stream>>>(x, Xp, 8.0f, H, N);

    dim3 grid(MT, VT);   // mTile fast -> consecutive blocks share the W panel (L2/L3 reuse)
    gemm_lse_partial<<<grid, 256, 0, stream>>>(Xp, Wp, partials, KC, V, VT);

    row_final<<<N, 256, 0, stream>>>(x, W, y, partials, nll, valid, H, V, VT);
    final_loss<<<1, 1024, 0, stream>>>(nll, valid, (float*)d_out, N);
}

// Round 5
// 1208.751 us; speedup vs baseline: 1.1166x; 1.0168x over previous
//
#include <hip/hip_runtime.h>
#include <hip/hip_bf16.h>
#include <math.h>

typedef unsigned char  u8;
typedef unsigned int   u32;
typedef __attribute__((ext_vector_type(8)))  int   int8v;
typedef __attribute__((ext_vector_type(16))) float f32x16;

#define IGNORE_INDEX (-100)

// ---------------- fp32 -> OCP e4m3 with explicit RNE ----------------
__device__ __forceinline__ u8 f32_to_e4m3(float f) {
    union { float f; u32 u; } v; v.f = f;
    u32 s  = (v.u >> 24) & 0x80u;
    u32 au = v.u & 0x7FFFFFFFu;
    float a = __uint_as_float(au);
    if (a >= 448.0f) return (u8)(s | 0x7E);          // clamp to max normal
    int e = (int)(au >> 23) - 127;
    if (e >= -6) {
        u32 m    = au & 0x7FFFFFu;
        u32 keep = m >> 20;
        u32 rest = m & 0xFFFFFu;
        keep += (rest > 0x80000u) || (rest == 0x80000u && (keep & 1u));
        u32 code = ((u32)(e + 7) << 3) + keep;        // mantissa carry bumps exponent
        if (code > 0x7E) code = 0x7E;
        return (u8)(s | code);
    } else {
        int q = (int)rintf(a * 512.0f);               // subnormal quantum 2^-9 (RNE)
        return (u8)(s | (u32)q);                      // q==8 lands on min-normal encoding
    }
}

// ---------------- fp32 -> fp8, packed into MFMA-fragment order ----------------
// P[panel][kc][s][lane][b], s = i2*4 + ks*2 + h; lane = khalf*32 + ln32
//   row = panel*128 + i2*32 + ln32
//   col = kc*128 + ks*64 + khalf*32 + h*16 + b
// Each fragment-half is 1024 CONTIGUOUS bytes -> the GEMM loads operands
// straight from global with one coalesced dwordx4 per lane.
__global__ __launch_bounds__(256) void cvt_pack_fp8(const float* __restrict__ in,
                                                    u8* __restrict__ out,
                                                    float scale, int H, int nRows) {
    __shared__ __align__(16) u8 lds[16384];
    const int kc    = blockIdx.x;
    const int panel = blockIdx.y;
    const int t     = threadIdx.x;

#pragma unroll
    for (int it = 0; it < 4; ++it) {
        int u  = it * 256 + t;          // 0..1023
        int r  = u >> 3;                // 0..127
        int cc = u & 7;                 // 16-col chunk within kc
        int row = panel * 128 + r;
        u8 tmp[16];
        if (row < nRows) {
            const float* src = in + (size_t)row * H + kc * 128 + cc * 16;
#pragma unroll
            for (int p = 0; p < 4; ++p) {
                float4 f = *(const float4*)(src + p * 4);
                tmp[p * 4 + 0] = f32_to_e4m3(f.x * scale);
                tmp[p * 4 + 1] = f32_to_e4m3(f.y * scale);
                tmp[p * 4 + 2] = f32_to_e4m3(f.z * scale);
                tmp[p * 4 + 3] = f32_to_e4m3(f.w * scale);
            }
        } else {
#pragma unroll
            for (int p = 0; p < 16; ++p) tmp[p] = 0;   // padded vocab rows -> 0.0
        }
        int i2 = r >> 5, ln32 = r & 31;
        int ks = cc >> 2, khalf = (cc >> 1) & 1, h = cc & 1;
        int s  = i2 * 4 + ks * 2 + h;
        int lane = khalf * 32 + ln32;
        *(int4*)(lds + s * 1024 + lane * 16) = *(const int4*)tmp;
    }
    __syncthreads();

    u8* dst = out + ((size_t)panel * gridDim.x + kc) * 16384;
    const int4* l4 = (const int4*)lds;
    int4* d4 = (int4*)dst;
#pragma unroll
    for (int p = 0; p < 4; ++p)
        d4[p * 256 + t] = l4[p * 256 + t];
}

// ---------------- fused MX-fp8 GEMM + online LSE partials, NO-LDS K-loop ----
// BM=BN=128, BK=128. 4 waves (2x2), each 64x64 via 2x2 mfma_scale 32x32x64.
// Operands are pre-packed so each fragment-half is 1024 contiguous bytes:
// waves load them global->VGPR (coalesced dwordx4), MFMA directly. ZERO
// barriers and zero LDS traffic in the K-loop -- waves free-run, vmcnt
// scheduling overlaps loads of iter k+1 with MFMAs of iter k (unroll 2).
// A/B bytes are each read by 2 waves of the block; the duplicate stream is
// L1-adjacent (same CU, near-lockstep) so L2 sees ~once-per-block traffic.
#define LD8(dst, base, off) { \
    int4 lo_ = *(const int4*)((base) + (off)); \
    int4 hi_ = *(const int4*)((base) + (off) + 1024); \
    dst[0]=lo_.x; dst[1]=lo_.y; dst[2]=lo_.z; dst[3]=lo_.w; \
    dst[4]=hi_.x; dst[5]=hi_.y; dst[6]=hi_.z; dst[7]=hi_.w; }

__global__ __launch_bounds__(256) void gemm_lse_partial(
    const u8* __restrict__ Ap,      // packed [MT][KC][16][64][16] fp8 (x*8)
    const u8* __restrict__ Bp,      // packed [VT][KC][16][64][16] fp8 (W*16)
    float2* __restrict__ partials,  // [N][VT]  (m, sumexp)
    int KC, int V, int VT)
{
    __shared__ float2 red[256];

    const int tid  = threadIdx.x;
    const int w    = tid >> 6;
    const int lane = tid & 63;
    const int wm   = w >> 1, wn = w & 1;
    const int ln32 = lane & 31;
    const int khalf = lane >> 5;

    const int mBase = blockIdx.x * 128;
    const int vTile = blockIdx.y;
    const int vBase = vTile * 128;

    f32x16 acc[2][2];
#pragma unroll
    for (int i = 0; i < 2; ++i)
#pragma unroll
        for (int j = 0; j < 2; ++j)
#pragma unroll
            for (int r = 0; r < 16; ++r) acc[i][j][r] = 0.0f;

    const int scaleA = 0x7C7C7C7C;  // E8M0 124 = 2^-3 (undo x*8)
    const int scaleB = 0x7B7B7B7B;  // E8M0 123 = 2^-4 (undo W*16)

    const u8* aPtr = Ap + ((size_t)blockIdx.x * KC) * 16384 + lane * 16;
    const u8* bPtr = Bp + ((size_t)vTile      * KC) * 16384 + lane * 16;

    // region byte offsets: s(i,ks) = ((w2+i)*4 + ks*2)*1024, halves +0/+1024
    const int aO0 = (wm * 2    ) * 4096;
    const int aO1 = (wm * 2 + 1) * 4096;
    const int bO0 = (wn * 2    ) * 4096;
    const int bO1 = (wn * 2 + 1) * 4096;

#pragma unroll 2
    for (int kc = 0; kc < KC; ++kc) {
        int8v a00, a10, b00, b10, a01, a11, b01, b11;
        // ks=0 operands first so the first 4 MFMAs can start early
        LD8(a00, aPtr, aO0);           LD8(a10, aPtr, aO1);
        LD8(b00, bPtr, bO0);           LD8(b10, bPtr, bO1);
        LD8(a01, aPtr, aO0 + 2048);    LD8(a11, aPtr, aO1 + 2048);
        LD8(b01, bPtr, bO0 + 2048);    LD8(b11, bPtr, bO1 + 2048);

        acc[0][0] = __builtin_amdgcn_mfma_scale_f32_32x32x64_f8f6f4(a00, b00, acc[0][0], 0, 0, 0, scaleA, 0, scaleB);
        acc[0][1] = __builtin_amdgcn_mfma_scale_f32_32x32x64_f8f6f4(a00, b10, acc[0][1], 0, 0, 0, scaleA, 0, scaleB);
        acc[1][0] = __builtin_amdgcn_mfma_scale_f32_32x32x64_f8f6f4(a10, b00, acc[1][0], 0, 0, 0, scaleA, 0, scaleB);
        acc[1][1] = __builtin_amdgcn_mfma_scale_f32_32x32x64_f8f6f4(a10, b10, acc[1][1], 0, 0, 0, scaleA, 0, scaleB);
        acc[0][0] = __builtin_amdgcn_mfma_scale_f32_32x32x64_f8f6f4(a01, b01, acc[0][0], 0, 0, 0, scaleA, 0, scaleB);
        acc[0][1] = __builtin_amdgcn_mfma_scale_f32_32x32x64_f8f6f4(a01, b11, acc[0][1], 0, 0, 0, scaleA, 0, scaleB);
        acc[1][0] = __builtin_amdgcn_mfma_scale_f32_32x32x64_f8f6f4(a11, b01, acc[1][0], 0, 0, 0, scaleA, 0, scaleB);
        acc[1][1] = __builtin_amdgcn_mfma_scale_f32_32x32x64_f8f6f4(a11, b11, acc[1][1], 0, 0, 0, scaleA, 0, scaleB);

        aPtr += 16384; bPtr += 16384;
    }

    // ---- online-softmax partial per row of the 128x128 tile ----
    // C/D 32x32 layout (m74/m101, fmt-independent): col=lane&31,
    // row=(reg&3)+8*(reg>>2)+4*(lane>>5).
    bool vj[2];
#pragma unroll
    for (int j = 0; j < 2; ++j)
        vj[j] = (vBase + wn * 64 + j * 32 + ln32) < V;

#pragma unroll
    for (int i = 0; i < 2; ++i) {
#pragma unroll
        for (int r = 0; r < 16; ++r) {
            float v0 = vj[0] ? acc[i][0][r] : -INFINITY;
            float v1 = vj[1] ? acc[i][1][r] : -INFINITY;
            float m = fmaxf(v0, v1);
#pragma unroll
            for (int o = 1; o < 32; o <<= 1)
                m = fmaxf(m, __shfl_xor(m, o, 64));
            float s = 0.0f;
            if (vj[0]) s += __expf(acc[i][0][r] - m);
            if (vj[1]) s += __expf(acc[i][1][r] - m);
#pragma unroll
            for (int o = 1; o < 32; o <<= 1)
                s += __shfl_xor(s, o, 64);
            if (ln32 == 0) {
                int row = wm * 64 + i * 32 + (r & 3) + 8 * (r >> 2) + 4 * khalf;
                red[row * 2 + wn] = make_float2(m, s);
            }
        }
    }
    __syncthreads();

    if (tid < 128) {
        float2 p0 = red[tid * 2 + 0];
        float2 p1 = red[tid * 2 + 1];
        float m = fmaxf(p0.x, p1.x);
        float s = p0.y * __expf(p0.x - m) + p1.y * __expf(p1.x - m);
        partials[(size_t)(mBase + tid) * VT + vTile] = make_float2(m, s);
    }
}

// ---------------- per-row: merge partials -> LSE, fp32 label dot ----------------
__global__ __launch_bounds__(256) void row_final(
    const float* __restrict__ x,      // [N][H] fp32
    const float* __restrict__ W,      // [V][H] fp32
    const int* __restrict__ y,        // [N]
    const float2* __restrict__ partials, // [N][VT]
    float* __restrict__ nll, float* __restrict__ valid,
    int H, int V, int VT)
{
    const int n = blockIdx.x;
    const int t = threadIdx.x;
    const int yn = y[n];
    const bool ok = (yn != IGNORE_INDEX);

    // label logit in full fp32
    float dsum = 0.0f;
    if (ok) {
        int cy = yn; if (cy < 0) cy = 0; if (cy >= V) cy = V - 1;
        const float4* xr = (const float4*)(x + (size_t)n * H);
        const float4* wr = (const float4*)(W + (size_t)cy * H);
        int nf4 = H >> 2;
        for (int i = t; i < nf4; i += 256) {
            float4 a = xr[i], b = wr[i];
            dsum += a.x * b.x + a.y * b.y + a.z * b.z + a.w * b.w;
        }
    }

    // merge this row's LSE partials
    float m = -INFINITY, s = 0.0f;
    const float2* pr = partials + (size_t)n * VT;
    for (int i = t; i < VT; i += 256) {
        float2 p = pr[i];
        float nm = fmaxf(m, p.x);
        s = s * __expf(m - nm) + p.y * __expf(p.x - nm);
        m = nm;
    }

    __shared__ float rm[256], rs[256], rd[256];
    rm[t] = m; rs[t] = s; rd[t] = dsum;
    __syncthreads();
    for (int o = 128; o > 0; o >>= 1) {
        if (t < o) {
            float m2 = rm[t + o], s2 = rs[t + o];
            float nm = fmaxf(rm[t], m2);
            rs[t] = rs[t] * __expf(rm[t] - nm) + s2 * __expf(m2 - nm);
            rm[t] = nm;
            rd[t] += rd[t + o];
        }
        __syncthreads();
    }
    if (t == 0) {
        float lse = rm[0] + __logf(rs[0]);
        nll[n]   = ok ? (lse - rd[0]) : 0.0f;
        valid[n] = ok ? 1.0f : 0.0f;
    }
}

// ---------------- final: loss = sum(nll) / max(sum(valid), 1) ----------------
__global__ __launch_bounds__(1024) void final_loss(
    const float* __restrict__ nll, const float* __restrict__ valid,
    float* __restrict__ out, int n)
{
    __shared__ float ss[1024], sv[1024];
    const int t = threadIdx.x;
    float a = 0.0f, b = 0.0f;
    for (int i = t; i < n; i += 1024) { a += nll[i]; b += valid[i]; }
    ss[t] = a; sv[t] = b;
    __syncthreads();
    for (int o = 512; o > 0; o >>= 1) {
        if (t < o) { ss[t] += ss[t + o]; sv[t] += sv[t + o]; }
        __syncthreads();
    }
    if (t == 0) out[0] = ss[0] / fmaxf(sv[0], 1.0f);
}

extern "C" void kernel_launch(void* const* d_in, const int* in_sizes, int n_in,
                              void* d_out, int out_size, void* d_ws, size_t ws_size,
                              hipStream_t stream) {
    const float* x = (const float*)d_in[0];
    const float* W = (const float*)d_in[1];
    const int*   y = (const int*)d_in[2];

    const long xsz = in_sizes[0];            // N*H
    const long wsz = in_sizes[1];            // V*H
    const int  N   = in_sizes[2];
    const int  H   = (int)(xsz / N);         // 2048
    const int  V   = (int)(wsz / H);         // 50257
    const int  VT  = (V + 127) / 128;        // 393
    const int  MT  = N / 128;                // 32
    const int  KC  = H / 128;                // 16

    char* ws = (char*)d_ws;
    size_t off = 0;
    u8* Wp = (u8*)(ws + off); off += (size_t)VT * KC * 16384; off = (off + 255) & ~(size_t)255;
    u8* Xp = (u8*)(ws + off); off += (size_t)MT * KC * 16384; off = (off + 255) & ~(size_t)255;
    float2* partials = (float2*)(ws + off); off += (size_t)N * VT * sizeof(float2); off = (off + 255) & ~(size_t)255;
    float* nll   = (float*)(ws + off); off += (size_t)N * 4;
    float* valid = (float*)(ws + off); off += (size_t)N * 4;

    cvt_pack_fp8<<<dim3(KC, VT), 256, 0, stream>>>(W, Wp, 16.0f, H, V);
    cvt_pack_fp8<<<dim3(KC, MT), 256, 0, stream>>>(x, Xp, 8.0f, H, N);

    dim3 grid(MT, VT);   // mTile fast -> consecutive blocks share the W panel (L2/L3 reuse)
    gemm_lse_partial<<<grid, 256, 0, stream>>>(Xp, Wp, partials, KC, V, VT);

    row_final<<<N, 256, 0, stream>>>(x, W, y, partials, nll, valid, H, V, VT);
    final_loss<<<1, 1024, 0, stream>>>(nll, valid, (float*)d_out, N);
}